// Round 12
// baseline (182.325 us; speedup 1.0000x reference)
//
#include <hip/hip_runtime.h>

#define BB 2
#define LL 512
#define DD 64
#define HH 8
#define GG 64
#define KK 4
#define NEGV -1e9f
#define NSLOT 36

typedef unsigned short ushort_t;
typedef __attribute__((ext_vector_type(8))) short bf16x8;
typedef __attribute__((ext_vector_type(4))) float f32x4;
#define MFMA(a, b, c) __builtin_amdgcn_mfma_f32_16x16x32_bf16(a, b, c, 0, 0, 0)

typedef const __attribute__((address_space(1))) unsigned int* gptr_t;
typedef __attribute__((address_space(3))) unsigned int* lptr_t;

__device__ __forceinline__ ushort_t f2b(float f) {
    unsigned int u = __float_as_uint(f);
    return (ushort_t)((u + 0x7FFFu + ((u >> 16) & 1u)) >> 16);
}
__device__ __forceinline__ float b2f(ushort_t s) {
    return __uint_as_float(((unsigned int)s) << 16);
}

// async global->LDS 16B: LDS dest = wave-uniform base + lane*16
__device__ __forceinline__ void gll16(const ushort_t* g, const ushort_t* l) {
    __builtin_amdgcn_global_load_lds(
        (gptr_t)(unsigned long long)g,
        (lptr_t)(unsigned int)(unsigned long long)l,
        16, 0, 0);
}

// async-stage a 64x64 bf16 tile: LDS linear, global source pre-XOR-swizzled.
__device__ __forceinline__ void stage64a(ushort_t* dst, const ushort_t* src,
                                         int rowstride, int tid) {
    int lane = tid & 63, w = tid >> 6;
#pragma unroll
    for (int h = 0; h < 2; ++h) {
        int g = h * 256 + w * 64 + lane;
        int row = g >> 3, colg = g & 7;
        gll16(src + (size_t)row * rowstride + ((colg ^ (row & 7)) << 3),
              dst + (size_t)(h * 256 + w * 64) * 8);
    }
}
// read an 8-elem fragment (col multiple of 8) from swizzled LDS tile
__device__ __forceinline__ bf16x8 frag(const ushort_t* s, int row, int col) {
    return *reinterpret_cast<const bf16x8*>(&s[(row << 6) + ((((col >> 3) ^ (row & 7))) << 3)]);
}
__device__ __forceinline__ bf16x8 maskfrag(bf16x8 v, int cnt, bool keep_prefix) {
    bf16x8 r;
#pragma unroll
    for (int u = 0; u < 8; ++u) {
        bool keep = keep_prefix ? (u < cnt) : (u >= cnt);
        r[u] = keep ? v[u] : (short)0;
    }
    return r;
}
__device__ __forceinline__ int iclamp(int v, int lo, int hi) {
    return v < lo ? lo : (v > hi ? hi : v);
}

// ---------------- K1: muxed {prepT 32 blk} {softmax_qz 256 blk} ----------------
__global__ __launch_bounds__(256) void k_prep(const float* __restrict__ T,
                                              const float* __restrict__ x,
                                              float* __restrict__ Qz,
                                              ushort_t* __restrict__ QzB,
                                              ushort_t* __restrict__ TB1,
                                              ushort_t* __restrict__ TB2) {
    int b = blockIdx.x;
    int tid = threadIdx.x;
    if (b < 32) {
        int k = b >> 3, c = b & 7;
        for (int g = tid; g < 512; g += 256) {
            int a = g >> 3, b0 = (g & 7) * 8;
            ushort_t o1[8], o2[8];
#pragma unroll
            for (int u = 0; u < 8; ++u) {
                o1[u] = f2b(T[(((k * 64 + a) * 64) + b0 + u) * 8 + c]);
                o2[u] = f2b(T[(((k * 64 + b0 + u) * 64) + a) * 8 + c]);
            }
            size_t base = ((size_t)(k * 8 + c) * 64 + a) * 64 + b0;
            *reinterpret_cast<uint4*>(&TB1[base]) = *reinterpret_cast<uint4*>(o1);
            *reinterpret_cast<uint4*>(&TB2[base]) = *reinterpret_cast<uint4*>(o2);
        }
    } else {
        int row = (b - 32) * 4 + (tid >> 6);
        int lane = tid & 63;
        float v = x[row * DD + lane];
        float m = v;
#pragma unroll
        for (int o = 32; o > 0; o >>= 1) m = fmaxf(m, __shfl_xor(m, o, 64));
        float e = __expf(v - m);
        float s = e;
#pragma unroll
        for (int o = 32; o > 0; o >>= 1) s += __shfl_xor(s, o, 64);
        float r = e / s;
        Qz[row * DD + lane] = r;
        QzB[row * DD + lane] = f2b(r);
    }
}

// ---------------- K2: fused M1/M2 MFMA + in-register collapse + band + qg ----------------
// grid 192: b<128 -> (jt,zc) Mcoll+band; b>=128 -> qg (16 rows each).
__global__ __launch_bounds__(256, 2) void k_Mcoll(const ushort_t* __restrict__ QzB,
        const ushort_t* __restrict__ TB1, const ushort_t* __restrict__ TB2,
        const float* __restrict__ dp, const float* __restrict__ Qz,
        const float* __restrict__ gp, const int* __restrict__ mask,
        ushort_t* __restrict__ M1Nb, ushort_t* __restrict__ M2Nb,
        ushort_t* __restrict__ MPNb, ushort_t* __restrict__ MMNb,
        ushort_t* __restrict__ MP2Nb, ushort_t* __restrict__ MM2Nb,
        ushort_t* __restrict__ MPT, ushort_t* __restrict__ MMT,
        ushort_t* __restrict__ MP2T, ushort_t* __restrict__ MM2T,
        float* __restrict__ BAND, float* __restrict__ QG) {
    __shared__ __align__(16) ushort_t smem[20480];   // 40 KB union
    __shared__ __align__(16) ushort_t sM1s[16384];   // 32 KB: [k][j_loc][a] bf16 M1 stash
    int tid = threadIdx.x;
    int b = blockIdx.x;
    if (b >= 128) {
        // ---- qg: 64 blocks x 16 rows ----
        float* gpS = reinterpret_cast<float*>(smem);   // [g][68]
#pragma unroll
        for (int idx = tid; idx < 4096; idx += 256) gpS[(idx >> 6) * 68 + (idx & 63)] = gp[idx];
        __syncthreads();
        int g = tid & 63;
        for (int rr = 0; rr < 4; ++rr) {
            int row = (b - 128) * 16 + rr * 4 + (tid >> 6);
            float qv = Qz[row * DD + g];
            float s = 0.f;
#pragma unroll 8
            for (int a = 0; a < 64; ++a) s += __shfl(qv, a, 64) * gpS[g * 68 + a];
            if (mask[row] == 0) s = NEGV;
            float m = s;
#pragma unroll
            for (int o = 32; o > 0; o >>= 1) m = fmaxf(m, __shfl_xor(m, o, 64));
            float e = __expf(s - m);
            float sum = e;
#pragma unroll
            for (int o = 32; o > 0; o >>= 1) sum += __shfl_xor(sum, o, 64);
            QG[row * GG + g] = e / sum;
        }
        return;
    }
    int jt = b & 7, zc = b >> 3;
    int z = zc >> 3, c = zc & 7;
    ushort_t* sQ = smem;                              // 4096
    stage64a(sQ, QzB + (size_t)(z * LL + jt * 64) * DD, DD, tid);
    stage64a(smem + 4096,  TB1 + (size_t)(0 * 8 + c) * 4096, 64, tid);   // sB1 buf0
    stage64a(smem + 12288, TB2 + (size_t)(0 * 8 + c) * 4096, 64, tid);   // sB2 buf0
    int w = tid >> 6, lm = tid & 15, lg = (tid & 63) >> 4;
    float w4[4], w5[4];
#pragma unroll
    for (int k = 0; k < 4; ++k) { w4[k] = dp[12 + k]; w5[k] = dp[16 + k]; }
    f32x4 cp1[4], cm1[4], cp2[4], cm2[4];
#pragma unroll
    for (int nf = 0; nf < 4; ++nf) {
        cp1[nf] = {0.f,0.f,0.f,0.f}; cm1[nf] = {0.f,0.f,0.f,0.f};
        cp2[nf] = {0.f,0.f,0.f,0.f}; cm2[nf] = {0.f,0.f,0.f,0.f};
    }
#pragma unroll
    for (int k = 0; k < 4; ++k) {
        __syncthreads();
        if (k < 3) {
            ushort_t* nb1 = smem + (((k + 1) & 1) ? 8192 : 4096);
            ushort_t* nb2 = smem + (((k + 1) & 1) ? 16384 : 12288);
            stage64a(nb1, TB1 + (size_t)((k + 1) * 8 + c) * 4096, 64, tid);
            stage64a(nb2, TB2 + (size_t)((k + 1) * 8 + c) * 4096, 64, tid);
        }
        const ushort_t* b1 = smem + ((k & 1) ? 8192 : 4096);
        const ushort_t* b2 = smem + ((k & 1) ? 16384 : 12288);
        f32x4 a1[4], a2[4];
#pragma unroll
        for (int nf = 0; nf < 4; ++nf) { a1[nf] = {0.f,0.f,0.f,0.f}; a2[nf] = {0.f,0.f,0.f,0.f}; }
#pragma unroll
        for (int ks = 0; ks < 2; ++ks) {
            int kc = ks * 32 + lg * 8;
            bf16x8 af = frag(sQ, w * 16 + lm, kc);
#pragma unroll
            for (int nf = 0; nf < 4; ++nf) {
                a1[nf] = MFMA(af, frag(b1, nf * 16 + lm, kc), a1[nf]);
                a2[nf] = MFMA(af, frag(b2, nf * 16 + lm, kc), a2[nf]);
            }
        }
        size_t base = (((size_t)z * KK + k) * HH + c) * LL;
#pragma unroll
        for (int nf = 0; nf < 4; ++nf)
#pragma unroll
            for (int r = 0; r < 4; ++r) {
                int jl = w * 16 + lg * 4 + r;
                int j = jt * 64 + jl;
                int a = nf * 16 + lm;
                float v1 = a1[nf][r], v2 = a2[nf][r];
                ushort_t v1b = f2b(v1);
                M1Nb[(base + j) * DD + a] = v1b;
                M2Nb[(base + j) * DD + a] = f2b(v2);
                sM1s[(k * 64 + jl) * 64 + a] = v1b;
                cp1[nf][r] += w4[k] * v1; cm1[nf][r] += w5[k] * v1;
                cp2[nf][r] += w4[k] * v2; cm2[nf][r] += w5[k] * v2;
            }
    }
    // natural-layout collapsed writes (direct from regs)
#pragma unroll
    for (int nf = 0; nf < 4; ++nf)
#pragma unroll
        for (int r = 0; r < 4; ++r) {
            int jl = w * 16 + lg * 4 + r;
            int a = nf * 16 + lm;
            size_t on = ((size_t)zc * LL + jt * 64 + jl) * DD + a;
            MPNb[on]  = f2b(cp1[nf][r]); MMNb[on]  = f2b(cm1[nf][r]);
            MP2Nb[on] = f2b(cp2[nf][r]); MM2Nb[on] = f2b(cm2[nf][r]);
        }
    __syncthreads();   // stash complete
    // ---- band epilogue: BAND[zc][j][d+3] from stash + Qz ----
    {
        int wave = tid >> 6, lane = tid & 63;
        for (int jj = 0; jj < 16; ++jj) {
            int j_loc = wave * 16 + jj;
            int j = jt * 64 + j_loc;
            float m0 = b2f(sM1s[(0 * 64 + j_loc) * 64 + lane]);
            float m1v = b2f(sM1s[(1 * 64 + j_loc) * 64 + lane]);
            float m2v = b2f(sM1s[(2 * 64 + j_loc) * 64 + lane]);
            float m3v = b2f(sM1s[(3 * 64 + j_loc) * 64 + lane]);
            float out = 0.f;
#pragma unroll
            for (int d = -3; d <= 3; ++d) {
                int i = j + d;
                if (i < 0 || i >= LL) continue;
                int idx = d < 0 ? d + 9 : d;
                float t = 0.f;
                if (idx != 0)
                    t = dp[(idx - 1) * 4 + 0] * m0 + dp[(idx - 1) * 4 + 1] * m1v
                      + dp[(idx - 1) * 4 + 2] * m2v + dp[(idx - 1) * 4 + 3] * m3v;
                float s = Qz[(z * LL + i) * DD + lane] * t;
#pragma unroll
                for (int o = 32; o > 0; o >>= 1) s += __shfl_xor(s, o, 64);
                if (lane == d + 3) out = s;
            }
            if (lane < 7) BAND[((size_t)zc * LL + j) * 8 + lane] = out;
        }
    }
    // transposed layouts via LDS (reuse smem; 4 arrays of 64x66)
    ushort_t* tr0 = smem;
    ushort_t* tr1 = smem + 4224;
    ushort_t* tr2 = smem + 8448;
    ushort_t* tr3 = smem + 12672;
#pragma unroll
    for (int nf = 0; nf < 4; ++nf)
#pragma unroll
        for (int r = 0; r < 4; ++r) {
            int jl = w * 16 + lg * 4 + r;
            int a = nf * 16 + lm;
            tr0[a * 66 + jl] = f2b(cp1[nf][r]); tr1[a * 66 + jl] = f2b(cm1[nf][r]);
            tr2[a * 66 + jl] = f2b(cp2[nf][r]); tr3[a * 66 + jl] = f2b(cm2[nf][r]);
        }
    __syncthreads();
    for (int g = tid; g < 512; g += 256) {
        int a = g >> 3, j0 = (g & 7) * 8;
        ushort_t o1[8], o2[8], o3[8], o4[8];
#pragma unroll
        for (int u = 0; u < 8; ++u) {
            o1[u] = tr0[a * 66 + j0 + u]; o2[u] = tr1[a * 66 + j0 + u];
            o3[u] = tr2[a * 66 + j0 + u]; o4[u] = tr3[a * 66 + j0 + u];
        }
        size_t ot = ((size_t)zc * DD + a) * LL + jt * 64 + j0;
        *reinterpret_cast<uint4*>(&MPT[ot])  = *reinterpret_cast<uint4*>(o1);
        *reinterpret_cast<uint4*>(&MMT[ot])  = *reinterpret_cast<uint4*>(o2);
        *reinterpret_cast<uint4*>(&MP2T[ot]) = *reinterpret_cast<uint4*>(o3);
        *reinterpret_cast<uint4*>(&MM2T[ot]) = *reinterpret_cast<uint4*>(o4);
    }
}

// ---------------- K4: fused s_h MFMA + band + mask + row-softmax + dual bf16 write ----------------
__global__ __launch_bounds__(256, 2) void k_shsm32(const ushort_t* __restrict__ QzB,
        const ushort_t* __restrict__ MPNb, const ushort_t* __restrict__ MMNb,
        const float* __restrict__ BAND, const int* __restrict__ mask,
        ushort_t* __restrict__ SHB, ushort_t* __restrict__ SHBT) {
    int ih = blockIdx.x, zc = blockIdx.y;
    int it = ih >> 1, rh = ih & 1;
    int z = zc >> 3;
    int R0 = it * 64 + rh * 32;
    __shared__ __align__(16) ushort_t sA[2048];
    __shared__ __align__(16) ushort_t sBd[4096];
    __shared__ __align__(16) ushort_t sB[2][8192];
    __shared__ __align__(16) ushort_t tl[2][32 * 72];
    __shared__ float redA[2][32], redB[2][32];
    int tid = threadIdx.x;
    int w = tid >> 6, lm = tid & 15, lg = (tid & 63) >> 4;
    int rw = w & 1, cw = w >> 1;
    {
        int row = tid >> 3, colg = tid & 7;
        gll16(&QzB[(size_t)(z * LL + R0 + row) * DD + ((colg ^ (row & 7)) << 3)],
              sA + (size_t)(w * 64) * 8);
    }
    stage64a(sBd, MMNb + ((size_t)zc * LL + it * 64) * DD, DD, tid);
    stage64a(sB[0], ((it >= 0) ? MPNb : MMNb) + ((size_t)zc * LL + 0 * 64) * DD, DD, tid);
    stage64a(sB[0] + 4096, ((it >= 4) ? MPNb : MMNb) + ((size_t)zc * LL + 4 * 64) * DD, DD, tid);
    f32x4 acc[4][4];
#pragma unroll
    for (int jl = 0; jl < 4; ++jl)
#pragma unroll
        for (int nf = 0; nf < 4; ++nf) acc[jl][nf] = {0.f, 0.f, 0.f, 0.f};
#pragma unroll
    for (int s = 0; s < 4; ++s) {
        __syncthreads();
        if (s < 3) {
            int jt0n = s + 1, jt1n = 5 + s;
            stage64a(sB[(s + 1) & 1],
                     ((it >= jt0n) ? MPNb : MMNb) + ((size_t)zc * LL + jt0n * 64) * DD, DD, tid);
            stage64a(sB[(s + 1) & 1] + 4096,
                     ((it >= jt1n) ? MPNb : MMNb) + ((size_t)zc * LL + jt1n * 64) * DD, DD, tid);
        }
        int jt0 = s, jt1 = 4 + s;
        int jtg = cw ? jt1 : jt0;
        const ushort_t* sBx = sB[s & 1] + (cw ? 4096 : 0);
#pragma unroll
        for (int ks = 0; ks < 2; ++ks) {
            int kc = ks * 32 + lg * 8;
            bf16x8 af = frag(sA, rw * 16 + lm, kc);
#pragma unroll
            for (int nf = 0; nf < 4; ++nf)
                acc[s][nf] = MFMA(af, frag(sBx, nf * 16 + lm, kc), acc[s][nf]);
        }
        if (jtg == it) {
            f32x4 accM[4];
#pragma unroll
            for (int nf = 0; nf < 4; ++nf) accM[nf] = {0.f, 0.f, 0.f, 0.f};
#pragma unroll
            for (int ks = 0; ks < 2; ++ks) {
                int kc = ks * 32 + lg * 8;
                bf16x8 af = frag(sA, rw * 16 + lm, kc);
#pragma unroll
                for (int nf = 0; nf < 4; ++nf)
                    accM[nf] = MFMA(af, frag(sBd, nf * 16 + lm, kc), accM[nf]);
            }
#pragma unroll
            for (int nf = 0; nf < 4; ++nf)
#pragma unroll
                for (int r = 0; r < 4; ++r) {
                    int i = R0 + rw * 16 + lg * 4 + r;
                    int j = it * 64 + nf * 16 + lm;
                    if (i <= j) acc[s][nf][r] = accM[nf][r];
                }
        }
    }
    int mi[4];
#pragma unroll
    for (int r = 0; r < 4; ++r) mi[r] = mask[z * LL + R0 + rw * 16 + lg * 4 + r];
#pragma unroll
    for (int jl = 0; jl < 4; ++jl) {
        int jtg = cw * 4 + jl;
#pragma unroll
        for (int nf = 0; nf < 4; ++nf) {
            int j = jtg * 64 + nf * 16 + lm;
            int mjv = mask[z * LL + j];
#pragma unroll
            for (int r = 0; r < 4; ++r) {
                int i = R0 + rw * 16 + lg * 4 + r;
                int d = i - j;
                float v = acc[jl][nf][r];
                if (d >= -3 && d <= 3) v = BAND[((size_t)zc * LL + j) * 8 + (d + 3)];
                if (!(mi[r] && mjv)) v = NEGV;
                acc[jl][nf][r] = v;
            }
        }
    }
    float gm[4], gs[4], inv[4];
#pragma unroll
    for (int r = 0; r < 4; ++r) {
        float m = -1e30f;
#pragma unroll
        for (int jl = 0; jl < 4; ++jl)
#pragma unroll
            for (int nf = 0; nf < 4; ++nf) m = fmaxf(m, acc[jl][nf][r]);
#pragma unroll
        for (int o = 1; o < 16; o <<= 1) m = fmaxf(m, __shfl_xor(m, o, 64));
        gm[r] = m;
    }
    if (lm == 0) {
#pragma unroll
        for (int r = 0; r < 4; ++r) redA[cw][rw * 16 + lg * 4 + r] = gm[r];
    }
    __syncthreads();
#pragma unroll
    for (int r = 0; r < 4; ++r)
        gm[r] = fmaxf(gm[r], redA[cw ^ 1][rw * 16 + lg * 4 + r]);
#pragma unroll
    for (int r = 0; r < 4; ++r) {
        float s = 0.f;
#pragma unroll
        for (int jl = 0; jl < 4; ++jl)
#pragma unroll
            for (int nf = 0; nf < 4; ++nf) {
                float e = __expf(acc[jl][nf][r] - gm[r]);
                acc[jl][nf][r] = e;
                s += e;
            }
#pragma unroll
        for (int o = 1; o < 16; o <<= 1) s += __shfl_xor(s, o, 64);
        gs[r] = s;
    }
    if (lm == 0) {
#pragma unroll
        for (int r = 0; r < 4; ++r) redB[cw][rw * 16 + lg * 4 + r] = gs[r];
    }
    __syncthreads();
#pragma unroll
    for (int r = 0; r < 4; ++r)
        inv[r] = 1.f / (gs[r] + redB[cw ^ 1][rw * 16 + lg * 4 + r]);
#pragma unroll
    for (int jl = 0; jl < 4; ++jl) {
        __syncthreads();
#pragma unroll
        for (int nf = 0; nf < 4; ++nf)
#pragma unroll
            for (int r = 0; r < 4; ++r)
                tl[cw][(rw * 16 + lg * 4 + r) * 72 + nf * 16 + lm] =
                    f2b(acc[jl][nf][r] * inv[r]);
        __syncthreads();
#pragma unroll
        for (int g = tid; g < 512; g += 256) {
            int cwg = g >> 8, rem = g & 255;
            int jtg = cwg * 4 + jl;
            int i_loc = rem >> 3, gj = rem & 7;
            ushort_t tmp[8];
#pragma unroll
            for (int u = 0; u < 8; ++u) tmp[u] = tl[cwg][i_loc * 72 + gj * 8 + u];
            *reinterpret_cast<uint4*>(
                &SHB[((size_t)zc * LL + R0 + i_loc) * LL + jtg * 64 + gj * 8]) =
                *reinterpret_cast<uint4*>(tmp);
        }
#pragma unroll
        for (int g = tid; g < 512; g += 256) {
            int cwg = g >> 8, rem = g & 255;
            int jtg = cwg * 4 + jl;
            int j_loc = rem >> 2, gi = rem & 3;
            ushort_t tmp2[8];
#pragma unroll
            for (int u = 0; u < 8; ++u) tmp2[u] = tl[cwg][(gi * 8 + u) * 72 + j_loc];
            *reinterpret_cast<uint4*>(
                &SHBT[((size_t)zc * LL + jtg * 64 + j_loc) * LL + R0 + gi * 8]) =
                *reinterpret_cast<uint4*>(tmp2);
        }
    }
}

// ---------------- K5: muxed {g12 GEMMs, double-buffered (512 blk)} {corr12 (1024 blk)} ----------------
__global__ __launch_bounds__(256, 4) void k_g12corr(const ushort_t* __restrict__ SHB,
        const ushort_t* __restrict__ SHBT,
        const ushort_t* __restrict__ MPT, const ushort_t* __restrict__ MMT,
        const ushort_t* __restrict__ MP2T, const ushort_t* __restrict__ MM2T,
        const ushort_t* __restrict__ M1Nb, const ushort_t* __restrict__ M2Nb,
        const ushort_t* __restrict__ MPNb, const ushort_t* __restrict__ MMNb,
        const ushort_t* __restrict__ MP2Nb, const ushort_t* __restrict__ MM2Nb,
        const float* __restrict__ dp, float* __restrict__ PG) {
    __shared__ __align__(16) ushort_t sSH[2][4096], sM[2][4096];
    int tid = threadIdx.x;
    int b = blockIdx.x;
    if (b < 512) {
        int it = b & 7, jc = (b >> 3) & 1, zcw = b >> 4;
        int which = zcw >> 4;
        int z = (zcw >> 3) & 1, c = zcw & 7;
        const ushort_t* Amat = which ? SHBT : SHB;
        const ushort_t* TP = which ? MP2T : MPT;
        const ushort_t* TM = which ? MM2T : MMT;
        int w = tid >> 6, lm = tid & 15, lg = (tid & 63) >> 4;
        size_t shbase = ((size_t)(z * HH + c) * LL + it * 64) * LL;
        size_t mbase  = ((size_t)(z * HH + c) * DD) * LL;
        int dgjs = ((it >> 2) == jc) ? (it & 3) : 99;
        int ns = (dgjs < 4) ? 5 : 4;
        auto getsub = [&](int t, const ushort_t*& shp, const ushort_t*& mp,
                          int& j0v, int& passv) {
            int js, pass;
            if (dgjs > 3)            { js = t;        pass = -1; }
            else if (t < dgjs)       { js = t;        pass = -1; }
            else if (t == dgjs)      { js = t;        pass = 0;  }
            else if (t == dgjs + 1)  { js = dgjs;     pass = 1;  }
            else                     { js = t - 1;    pass = -1; }
            int j0 = jc * 256 + js * 64;
            bool useP = (pass == -1)
                        ? (which == 0 ? (j0 < it * 64) : (j0 > it * 64))
                        : (pass == 0);
            shp = Amat + shbase + j0;
            mp  = (useP ? TP : TM) + mbase + j0;
            j0v = j0; passv = pass;
        };
        f32x4 acc[4];
#pragma unroll
        for (int nf = 0; nf < 4; ++nf) acc[nf] = {0.f,0.f,0.f,0.f};
        {
            const ushort_t *shp, *mp; int j0v, pv;
            getsub(0, shp, mp, j0v, pv);
            stage64a(sSH[0], shp, LL, tid);
            stage64a(sM[0], mp, LL, tid);
        }
        for (int t = 0; t < ns; ++t) {
            __syncthreads();
            if (t + 1 < ns) {
                const ushort_t *shp, *mp; int j0v, pv;
                getsub(t + 1, shp, mp, j0v, pv);
                stage64a(sSH[(t + 1) & 1], shp, LL, tid);
                stage64a(sM[(t + 1) & 1], mp, LL, tid);
            }
            const ushort_t *shp_, *mp_; int j0v, pv;
            getsub(t, shp_, mp_, j0v, pv);
            const ushort_t* sshx = sSH[t & 1];
            const ushort_t* smx = sM[t & 1];
#pragma unroll
            for (int ks = 0; ks < 2; ++ks) {
                int kc = ks * 32 + lg * 8;
                int jb = j0v + kc;
                bf16x8 af = frag(sshx, w * 16 + lm, kc);
                if (pv >= 0) {
                    int i = it * 64 + w * 16 + lm;
                    int cnt = (which == 0) ? iclamp(i - jb, 0, 8) : iclamp(i + 1 - jb, 0, 8);
                    af = maskfrag(af, cnt, (pv == 0) == (which == 0));
                }
#pragma unroll
                for (int nf = 0; nf < 4; ++nf)
                    acc[nf] = MFMA(af, frag(smx, nf * 16 + lm, kc), acc[nf]);
            }
        }
        int slot = which * 16 + c * 2 + jc;
#pragma unroll
        for (int nf = 0; nf < 4; ++nf)
#pragma unroll
            for (int r = 0; r < 4; ++r) {
                int i = it * 64 + w * 16 + lg * 4 + r;
                int a = nf * 16 + lm;
                PG[((size_t)(slot * BB + z) * LL + i) * DD + a] = acc[nf][r];
            }
    } else {
        int bid = b - 512;
        int which = bid >> 9; bid &= 511;
        int w = bid * 4 + (tid >> 6);
        int lane = tid & 63;
        int ch = w & 1, i = (w >> 1) & 511, z = w >> 10;
        const ushort_t* Mx = which ? M2Nb : M1Nb;
        const ushort_t* MPb = which ? MP2Nb : MPNb;
        const ushort_t* MMb = which ? MM2Nb : MMNb;
        float acc = 0.f;
        for (int cc = 0; cc < 4; ++cc) {
            int c = ch * 4 + cc;
#pragma unroll
            for (int d = -3; d <= 3; ++d) {
                int j = which ? i + d : i - d;
                if (j < 0 || j >= LL) continue;
                float qh = which ? b2f(SHB[(((size_t)z * HH + c) * LL + j) * LL + i])
                                 : b2f(SHB[(((size_t)z * HH + c) * LL + i) * LL + j]);
                int idx = d < 0 ? d + 9 : d;
                float e = 0.f;
                if (idx != 0) {
#pragma unroll
                    for (int k = 0; k < 4; ++k)
                        e += dp[(idx - 1) * 4 + k] *
                             b2f(Mx[((((size_t)z * KK + k) * HH + c) * LL + j) * DD + lane]);
                }
                const ushort_t* mb = (d > 0) ? MPb : MMb;
                float mn = b2f(mb[(((size_t)z * HH + c) * LL + j) * DD + lane]);
                acc += qh * (e - mn);
            }
        }
        int slot = 32 + which * 2 + ch;
        PG[(((size_t)slot * BB + z) * LL + i) * DD + lane] = acc;
    }
}

// ---------------- K6a: mid-iteration update: q = x + msgs, then softmax -> Qz/QzB ----------------
__global__ __launch_bounds__(256) void k_update_sm(const float* __restrict__ x,
                         const float* __restrict__ PG, const float* __restrict__ QG,
                         const float* __restrict__ gp,
                         float* __restrict__ Qz, ushort_t* __restrict__ QzB) {
    __shared__ __align__(16) float gpS[64][68];
    int tid = threadIdx.x;
#pragma unroll
    for (int idx = tid; idx < 4096; idx += 256) gpS[idx >> 6][idx & 63] = gp[idx];
    __syncthreads();
    int row = blockIdx.x * 4 + (tid >> 6);
    int a = tid & 63;
    float acc = x[row * DD + a];
    float qgv = QG[row * GG + a];
#pragma unroll 8
    for (int g = 0; g < 64; ++g) acc += __shfl(qgv, g, 64) * gpS[g][a];
#pragma unroll 6
    for (int s = 0; s < NSLOT; ++s) acc += PG[((size_t)s * BB * LL + row) * DD + a];
    float m = acc;
#pragma unroll
    for (int o = 32; o > 0; o >>= 1) m = fmaxf(m, __shfl_xor(m, o, 64));
    float e = __expf(acc - m);
    float s2 = e;
#pragma unroll
    for (int o = 32; o > 0; o >>= 1) s2 += __shfl_xor(s2, o, 64);
    float r = e / s2;
    Qz[row * DD + a] = r;
    QzB[row * DD + a] = f2b(r);
}

// ---------------- K6b: final update: out = x + msgs ----------------
__global__ __launch_bounds__(256) void k_update_fin(const float* __restrict__ x,
                         const float* __restrict__ PG, const float* __restrict__ QG,
                         const float* __restrict__ gp, float* __restrict__ outq) {
    __shared__ __align__(16) float gpS[64][68];
    int tid = threadIdx.x;
#pragma unroll
    for (int idx = tid; idx < 4096; idx += 256) gpS[idx >> 6][idx & 63] = gp[idx];
    __syncthreads();
    int row = blockIdx.x * 4 + (tid >> 6);
    int a = tid & 63;
    float acc = x[row * DD + a];
    float qgv = QG[row * GG + a];
#pragma unroll 8
    for (int g = 0; g < 64; ++g) acc += __shfl(qgv, g, 64) * gpS[g][a];
#pragma unroll 6
    for (int s = 0; s < NSLOT; ++s) acc += PG[((size_t)s * BB * LL + row) * DD + a];
    outq[row * DD + a] = acc;
}

extern "C" void kernel_launch(void* const* d_in, const int* in_sizes, int n_in,
                              void* d_out, int out_size, void* d_ws, size_t ws_size,
                              hipStream_t stream) {
    const float* x    = (const float*)d_in[0];
    const int*   mask = (const int*)d_in[1];
    const float* dp   = (const float*)d_in[2];
    const float* T    = (const float*)d_in[3];
    const float* gp   = (const float*)d_in[4];
    float* out = (float*)d_out;

    float* p = (float*)d_ws;
    float* Qz = p;                        p += 65536;
    ushort_t* QzB = (ushort_t*)p;         p += 32768;
    ushort_t* TB1 = (ushort_t*)p;         p += 65536;
    ushort_t* TB2 = (ushort_t*)p;         p += 65536;
    ushort_t* M1Nb = (ushort_t*)p;        p += 1048576;
    ushort_t* M2Nb = (ushort_t*)p;        p += 1048576;
    ushort_t* MPNb  = (ushort_t*)p;       p += 262144;
    ushort_t* MMNb  = (ushort_t*)p;       p += 262144;
    ushort_t* MP2Nb = (ushort_t*)p;       p += 262144;
    ushort_t* MM2Nb = (ushort_t*)p;       p += 262144;
    ushort_t* MPT   = (ushort_t*)p;       p += 262144;
    ushort_t* MMT   = (ushort_t*)p;       p += 262144;
    ushort_t* MP2T  = (ushort_t*)p;       p += 262144;
    ushort_t* MM2T  = (ushort_t*)p;       p += 262144;
    float* BAND = p;                      p += 65536;
    ushort_t* SHB  = (ushort_t*)p;        p += 2097152;
    ushort_t* SHBT = (ushort_t*)p;        p += 2097152;
    float* QG   = p;                      p += 65536;
    float* PG   = p;                      p += (size_t)NSLOT * 65536;

    hipLaunchKernelGGL(k_prep, dim3(288), dim3(256), 0, stream, T, x, Qz, QzB, TB1, TB2);

    for (int iter = 0; iter < 2; ++iter) {
        hipLaunchKernelGGL(k_Mcoll, dim3(192), dim3(256), 0, stream, QzB, TB1, TB2, dp,
                           Qz, gp, mask,
                           M1Nb, M2Nb, MPNb, MMNb, MP2Nb, MM2Nb, MPT, MMT, MP2T, MM2T,
                           BAND, QG);
        hipLaunchKernelGGL(k_shsm32, dim3(16, 16), dim3(256), 0, stream, QzB, MPNb, MMNb, BAND, mask,
                           SHB, SHBT);
        hipLaunchKernelGGL(k_g12corr, dim3(1536), dim3(256), 0, stream, SHB, SHBT,
                           MPT, MMT, MP2T, MM2T, M1Nb, M2Nb,
                           MPNb, MMNb, MP2Nb, MM2Nb, dp, PG);
        if (iter == 0)
            hipLaunchKernelGGL(k_update_sm, dim3(256), dim3(256), 0, stream, x, PG, QG, gp, Qz, QzB);
        else
            hipLaunchKernelGGL(k_update_fin, dim3(256), dim3(256), 0, stream, x, PG, QG, gp, out);
    }
}

// Round 13
// 123.481 us; speedup vs baseline: 1.4765x; 1.4765x over previous
//
#include <hip/hip_runtime.h>

#define BB 2
#define LL 512
#define DD 64
#define HH 8
#define GG 64
#define KK 4
#define NEGV -1e9f
#define NSLOT 36

typedef unsigned short ushort_t;
typedef __attribute__((ext_vector_type(8))) short bf16x8;
typedef __attribute__((ext_vector_type(4))) float f32x4;
#define MFMA(a, b, c) __builtin_amdgcn_mfma_f32_16x16x32_bf16(a, b, c, 0, 0, 0)

typedef const __attribute__((address_space(1))) unsigned int* gptr_t;
typedef __attribute__((address_space(3))) unsigned int* lptr_t;

__device__ __forceinline__ ushort_t f2b(float f) {
    unsigned int u = __float_as_uint(f);
    return (ushort_t)((u + 0x7FFFu + ((u >> 16) & 1u)) >> 16);
}
__device__ __forceinline__ float b2f(ushort_t s) {
    return __uint_as_float(((unsigned int)s) << 16);
}

// async global->LDS 16B: LDS dest = wave-uniform base + lane*16
__device__ __forceinline__ void gll16(const ushort_t* g, const ushort_t* l) {
    __builtin_amdgcn_global_load_lds(
        (gptr_t)(unsigned long long)g,
        (lptr_t)(unsigned int)(unsigned long long)l,
        16, 0, 0);
}

// async-stage a 64x64 bf16 tile: LDS linear, global source pre-XOR-swizzled.
__device__ __forceinline__ void stage64a(ushort_t* dst, const ushort_t* src,
                                         int rowstride, int tid) {
    int lane = tid & 63, w = tid >> 6;
#pragma unroll
    for (int h = 0; h < 2; ++h) {
        int g = h * 256 + w * 64 + lane;
        int row = g >> 3, colg = g & 7;
        gll16(src + (size_t)row * rowstride + ((colg ^ (row & 7)) << 3),
              dst + (size_t)(h * 256 + w * 64) * 8);
    }
}
// read an 8-elem fragment (col multiple of 8) from swizzled LDS tile
__device__ __forceinline__ bf16x8 frag(const ushort_t* s, int row, int col) {
    return *reinterpret_cast<const bf16x8*>(&s[(row << 6) + ((((col >> 3) ^ (row & 7))) << 3)]);
}
__device__ __forceinline__ bf16x8 maskfrag(bf16x8 v, int cnt, bool keep_prefix) {
    bf16x8 r;
#pragma unroll
    for (int u = 0; u < 8; ++u) {
        bool keep = keep_prefix ? (u < cnt) : (u >= cnt);
        r[u] = keep ? v[u] : (short)0;
    }
    return r;
}
__device__ __forceinline__ int iclamp(int v, int lo, int hi) {
    return v < lo ? lo : (v > hi ? hi : v);
}

// ---------------- K1: muxed {prepT 32 blk} {softmax_qz + qg 256 blk} ----------------
__global__ __launch_bounds__(256) void k_prep(const float* __restrict__ T,
                                              const float* __restrict__ x,
                                              const float* __restrict__ gp,
                                              const int* __restrict__ mask,
                                              float* __restrict__ Qz,
                                              ushort_t* __restrict__ QzB,
                                              ushort_t* __restrict__ TB1,
                                              ushort_t* __restrict__ TB2,
                                              float* __restrict__ QG) {
    int b = blockIdx.x;
    int tid = threadIdx.x;
    if (b < 32) {
        int k = b >> 3, c = b & 7;
        for (int g = tid; g < 512; g += 256) {
            int a = g >> 3, b0 = (g & 7) * 8;
            ushort_t o1[8], o2[8];
#pragma unroll
            for (int u = 0; u < 8; ++u) {
                o1[u] = f2b(T[(((k * 64 + a) * 64) + b0 + u) * 8 + c]);
                o2[u] = f2b(T[(((k * 64 + b0 + u) * 64) + a) * 8 + c]);
            }
            size_t base = ((size_t)(k * 8 + c) * 64 + a) * 64 + b0;
            *reinterpret_cast<uint4*>(&TB1[base]) = *reinterpret_cast<uint4*>(o1);
            *reinterpret_cast<uint4*>(&TB2[base]) = *reinterpret_cast<uint4*>(o2);
        }
    } else {
        __shared__ __align__(16) float gpS[64 * 68];
#pragma unroll
        for (int idx = tid; idx < 4096; idx += 256) gpS[(idx >> 6) * 68 + (idx & 63)] = gp[idx];
        __syncthreads();
        int row = (b - 32) * 4 + (tid >> 6);
        int lane = tid & 63;
        float v = x[row * DD + lane];
        float m = v;
#pragma unroll
        for (int o = 32; o > 0; o >>= 1) m = fmaxf(m, __shfl_xor(m, o, 64));
        float e = __expf(v - m);
        float s = e;
#pragma unroll
        for (int o = 32; o > 0; o >>= 1) s += __shfl_xor(s, o, 64);
        float r = e / s;
        Qz[row * DD + lane] = r;
        QzB[row * DD + lane] = f2b(r);
        // qg from in-register row
        float sg = 0.f;
#pragma unroll 8
        for (int a = 0; a < 64; ++a) sg += __shfl(r, a, 64) * gpS[lane * 68 + a];
        if (mask[row] == 0) sg = NEGV;
        float mg = sg;
#pragma unroll
        for (int o = 32; o > 0; o >>= 1) mg = fmaxf(mg, __shfl_xor(mg, o, 64));
        float eg = __expf(sg - mg);
        float sumg = eg;
#pragma unroll
        for (int o = 32; o > 0; o >>= 1) sumg += __shfl_xor(sumg, o, 64);
        QG[row * GG + lane] = eg / sumg;
    }
}

// ---------------- K2: fused M1/M2 MFMA + in-register collapse + lane-parallel band ----------------
// grid (8 jt, 16 zc)
__global__ __launch_bounds__(256, 2) void k_Mcoll(const ushort_t* __restrict__ QzB,
        const ushort_t* __restrict__ TB1, const ushort_t* __restrict__ TB2,
        const float* __restrict__ dp, const float* __restrict__ Qz,
        ushort_t* __restrict__ M1Nb, ushort_t* __restrict__ M2Nb,
        ushort_t* __restrict__ MPNb, ushort_t* __restrict__ MMNb,
        ushort_t* __restrict__ MP2Nb, ushort_t* __restrict__ MM2Nb,
        ushort_t* __restrict__ MPT, ushort_t* __restrict__ MMT,
        ushort_t* __restrict__ MP2T, ushort_t* __restrict__ MM2T,
        float* __restrict__ BAND) {
    int jt = blockIdx.x, zc = blockIdx.y;
    int z = zc >> 3, c = zc & 7;
    __shared__ __align__(16) ushort_t smem[20480];   // 40 KB union
    __shared__ __align__(16) ushort_t sM1s[16384];   // 32 KB: [k][j_loc][a] bf16 M1 stash
    int tid = threadIdx.x;
    ushort_t* sQ = smem;                              // 4096
    stage64a(sQ, QzB + (size_t)(z * LL + jt * 64) * DD, DD, tid);
    stage64a(smem + 4096,  TB1 + (size_t)(0 * 8 + c) * 4096, 64, tid);   // sB1 buf0
    stage64a(smem + 12288, TB2 + (size_t)(0 * 8 + c) * 4096, 64, tid);   // sB2 buf0
    int w = tid >> 6, lm = tid & 15, lg = (tid & 63) >> 4;
    float w4[4], w5[4];
#pragma unroll
    for (int k = 0; k < 4; ++k) { w4[k] = dp[12 + k]; w5[k] = dp[16 + k]; }
    f32x4 cp1[4], cm1[4], cp2[4], cm2[4];
#pragma unroll
    for (int nf = 0; nf < 4; ++nf) {
        cp1[nf] = {0.f,0.f,0.f,0.f}; cm1[nf] = {0.f,0.f,0.f,0.f};
        cp2[nf] = {0.f,0.f,0.f,0.f}; cm2[nf] = {0.f,0.f,0.f,0.f};
    }
#pragma unroll
    for (int k = 0; k < 4; ++k) {
        __syncthreads();
        if (k < 3) {
            ushort_t* nb1 = smem + (((k + 1) & 1) ? 8192 : 4096);
            ushort_t* nb2 = smem + (((k + 1) & 1) ? 16384 : 12288);
            stage64a(nb1, TB1 + (size_t)((k + 1) * 8 + c) * 4096, 64, tid);
            stage64a(nb2, TB2 + (size_t)((k + 1) * 8 + c) * 4096, 64, tid);
        }
        const ushort_t* b1 = smem + ((k & 1) ? 8192 : 4096);
        const ushort_t* b2 = smem + ((k & 1) ? 16384 : 12288);
        f32x4 a1[4], a2[4];
#pragma unroll
        for (int nf = 0; nf < 4; ++nf) { a1[nf] = {0.f,0.f,0.f,0.f}; a2[nf] = {0.f,0.f,0.f,0.f}; }
#pragma unroll
        for (int ks = 0; ks < 2; ++ks) {
            int kc = ks * 32 + lg * 8;
            bf16x8 af = frag(sQ, w * 16 + lm, kc);
#pragma unroll
            for (int nf = 0; nf < 4; ++nf) {
                a1[nf] = MFMA(af, frag(b1, nf * 16 + lm, kc), a1[nf]);
                a2[nf] = MFMA(af, frag(b2, nf * 16 + lm, kc), a2[nf]);
            }
        }
        size_t base = (((size_t)z * KK + k) * HH + c) * LL;
#pragma unroll
        for (int nf = 0; nf < 4; ++nf)
#pragma unroll
            for (int r = 0; r < 4; ++r) {
                int jl = w * 16 + lg * 4 + r;
                int j = jt * 64 + jl;
                int a = nf * 16 + lm;
                float v1 = a1[nf][r], v2 = a2[nf][r];
                ushort_t v1b = f2b(v1);
                M1Nb[(base + j) * DD + a] = v1b;
                M2Nb[(base + j) * DD + a] = f2b(v2);
                sM1s[(k * 64 + jl) * 64 + a] = v1b;
                cp1[nf][r] += w4[k] * v1; cm1[nf][r] += w5[k] * v1;
                cp2[nf][r] += w4[k] * v2; cm2[nf][r] += w5[k] * v2;
            }
    }
    // natural-layout collapsed writes (direct from regs)
#pragma unroll
    for (int nf = 0; nf < 4; ++nf)
#pragma unroll
        for (int r = 0; r < 4; ++r) {
            int jl = w * 16 + lg * 4 + r;
            int a = nf * 16 + lm;
            size_t on = ((size_t)zc * LL + jt * 64 + jl) * DD + a;
            MPNb[on]  = f2b(cp1[nf][r]); MMNb[on]  = f2b(cm1[nf][r]);
            MP2Nb[on] = f2b(cp2[nf][r]); MM2Nb[on] = f2b(cm2[nf][r]);
        }
    __syncthreads();   // stash complete; smem free
    // ---- lane-parallel band: 448 outputs = 64 j_loc x 7 dIdx, no cross-lane deps ----
    for (int o = tid; o < 448; o += 256) {
        int j_loc = o / 7, dIdx = o % 7, d = dIdx - 3;
        int j = jt * 64 + j_loc;
        int i = j + d;
        float acc = 0.f;
        if (d != 0 && i >= 0 && i < LL) {
            int idx = d < 0 ? d + 9 : d;
            float k0 = dp[(idx - 1) * 4 + 0], k1 = dp[(idx - 1) * 4 + 1];
            float k2 = dp[(idx - 1) * 4 + 2], k3 = dp[(idx - 1) * 4 + 3];
            const float* qrow = Qz + (size_t)(z * LL + i) * DD;
#pragma unroll 8
            for (int a = 0; a < 64; ++a) {
                float t = k0 * b2f(sM1s[(0 * 64 + j_loc) * 64 + a])
                        + k1 * b2f(sM1s[(1 * 64 + j_loc) * 64 + a])
                        + k2 * b2f(sM1s[(2 * 64 + j_loc) * 64 + a])
                        + k3 * b2f(sM1s[(3 * 64 + j_loc) * 64 + a]);
                acc += qrow[a] * t;
            }
        }
        BAND[((size_t)zc * LL + j) * 8 + dIdx] = acc;
    }
    // transposed layouts via LDS (reuse smem; 4 arrays of 64x66)
    ushort_t* tr0 = smem;
    ushort_t* tr1 = smem + 4224;
    ushort_t* tr2 = smem + 8448;
    ushort_t* tr3 = smem + 12672;
#pragma unroll
    for (int nf = 0; nf < 4; ++nf)
#pragma unroll
        for (int r = 0; r < 4; ++r) {
            int jl = w * 16 + lg * 4 + r;
            int a = nf * 16 + lm;
            tr0[a * 66 + jl] = f2b(cp1[nf][r]); tr1[a * 66 + jl] = f2b(cm1[nf][r]);
            tr2[a * 66 + jl] = f2b(cp2[nf][r]); tr3[a * 66 + jl] = f2b(cm2[nf][r]);
        }
    __syncthreads();
    for (int g = tid; g < 512; g += 256) {
        int a = g >> 3, j0 = (g & 7) * 8;
        ushort_t o1[8], o2[8], o3[8], o4[8];
#pragma unroll
        for (int u = 0; u < 8; ++u) {
            o1[u] = tr0[a * 66 + j0 + u]; o2[u] = tr1[a * 66 + j0 + u];
            o3[u] = tr2[a * 66 + j0 + u]; o4[u] = tr3[a * 66 + j0 + u];
        }
        size_t ot = ((size_t)zc * DD + a) * LL + jt * 64 + j0;
        *reinterpret_cast<uint4*>(&MPT[ot])  = *reinterpret_cast<uint4*>(o1);
        *reinterpret_cast<uint4*>(&MMT[ot])  = *reinterpret_cast<uint4*>(o2);
        *reinterpret_cast<uint4*>(&MP2T[ot]) = *reinterpret_cast<uint4*>(o3);
        *reinterpret_cast<uint4*>(&MM2T[ot]) = *reinterpret_cast<uint4*>(o4);
    }
}

// ---------------- K4: fused s_h MFMA + band + mask + row-softmax + dual bf16 write ----------------
__global__ __launch_bounds__(256, 2) void k_shsm32(const ushort_t* __restrict__ QzB,
        const ushort_t* __restrict__ MPNb, const ushort_t* __restrict__ MMNb,
        const float* __restrict__ BAND, const int* __restrict__ mask,
        ushort_t* __restrict__ SHB, ushort_t* __restrict__ SHBT) {
    int ih = blockIdx.x, zc = blockIdx.y;
    int it = ih >> 1, rh = ih & 1;
    int z = zc >> 3;
    int R0 = it * 64 + rh * 32;
    __shared__ __align__(16) ushort_t sA[2048];
    __shared__ __align__(16) ushort_t sBd[4096];
    __shared__ __align__(16) ushort_t sB[2][8192];
    __shared__ __align__(16) ushort_t tl[2][32 * 72];
    __shared__ float redA[2][32], redB[2][32];
    int tid = threadIdx.x;
    int w = tid >> 6, lm = tid & 15, lg = (tid & 63) >> 4;
    int rw = w & 1, cw = w >> 1;
    {
        int row = tid >> 3, colg = tid & 7;
        gll16(&QzB[(size_t)(z * LL + R0 + row) * DD + ((colg ^ (row & 7)) << 3)],
              sA + (size_t)(w * 64) * 8);
    }
    stage64a(sBd, MMNb + ((size_t)zc * LL + it * 64) * DD, DD, tid);
    stage64a(sB[0], ((it >= 0) ? MPNb : MMNb) + ((size_t)zc * LL + 0 * 64) * DD, DD, tid);
    stage64a(sB[0] + 4096, ((it >= 4) ? MPNb : MMNb) + ((size_t)zc * LL + 4 * 64) * DD, DD, tid);
    f32x4 acc[4][4];
#pragma unroll
    for (int jl = 0; jl < 4; ++jl)
#pragma unroll
        for (int nf = 0; nf < 4; ++nf) acc[jl][nf] = {0.f, 0.f, 0.f, 0.f};
#pragma unroll
    for (int s = 0; s < 4; ++s) {
        __syncthreads();
        if (s < 3) {
            int jt0n = s + 1, jt1n = 5 + s;
            stage64a(sB[(s + 1) & 1],
                     ((it >= jt0n) ? MPNb : MMNb) + ((size_t)zc * LL + jt0n * 64) * DD, DD, tid);
            stage64a(sB[(s + 1) & 1] + 4096,
                     ((it >= jt1n) ? MPNb : MMNb) + ((size_t)zc * LL + jt1n * 64) * DD, DD, tid);
        }
        int jt0 = s, jt1 = 4 + s;
        int jtg = cw ? jt1 : jt0;
        const ushort_t* sBx = sB[s & 1] + (cw ? 4096 : 0);
#pragma unroll
        for (int ks = 0; ks < 2; ++ks) {
            int kc = ks * 32 + lg * 8;
            bf16x8 af = frag(sA, rw * 16 + lm, kc);
#pragma unroll
            for (int nf = 0; nf < 4; ++nf)
                acc[s][nf] = MFMA(af, frag(sBx, nf * 16 + lm, kc), acc[s][nf]);
        }
        if (jtg == it) {
            f32x4 accM[4];
#pragma unroll
            for (int nf = 0; nf < 4; ++nf) accM[nf] = {0.f, 0.f, 0.f, 0.f};
#pragma unroll
            for (int ks = 0; ks < 2; ++ks) {
                int kc = ks * 32 + lg * 8;
                bf16x8 af = frag(sA, rw * 16 + lm, kc);
#pragma unroll
                for (int nf = 0; nf < 4; ++nf)
                    accM[nf] = MFMA(af, frag(sBd, nf * 16 + lm, kc), accM[nf]);
            }
#pragma unroll
            for (int nf = 0; nf < 4; ++nf)
#pragma unroll
                for (int r = 0; r < 4; ++r) {
                    int i = R0 + rw * 16 + lg * 4 + r;
                    int j = it * 64 + nf * 16 + lm;
                    if (i <= j) acc[s][nf][r] = accM[nf][r];
                }
        }
    }
    int mi[4];
#pragma unroll
    for (int r = 0; r < 4; ++r) mi[r] = mask[z * LL + R0 + rw * 16 + lg * 4 + r];
#pragma unroll
    for (int jl = 0; jl < 4; ++jl) {
        int jtg = cw * 4 + jl;
#pragma unroll
        for (int nf = 0; nf < 4; ++nf) {
            int j = jtg * 64 + nf * 16 + lm;
            int mjv = mask[z * LL + j];
#pragma unroll
            for (int r = 0; r < 4; ++r) {
                int i = R0 + rw * 16 + lg * 4 + r;
                int d = i - j;
                float v = acc[jl][nf][r];
                if (d >= -3 && d <= 3) v = BAND[((size_t)zc * LL + j) * 8 + (d + 3)];
                if (!(mi[r] && mjv)) v = NEGV;
                acc[jl][nf][r] = v;
            }
        }
    }
    float gm[4], gs[4], inv[4];
#pragma unroll
    for (int r = 0; r < 4; ++r) {
        float m = -1e30f;
#pragma unroll
        for (int jl = 0; jl < 4; ++jl)
#pragma unroll
            for (int nf = 0; nf < 4; ++nf) m = fmaxf(m, acc[jl][nf][r]);
#pragma unroll
        for (int o = 1; o < 16; o <<= 1) m = fmaxf(m, __shfl_xor(m, o, 64));
        gm[r] = m;
    }
    if (lm == 0) {
#pragma unroll
        for (int r = 0; r < 4; ++r) redA[cw][rw * 16 + lg * 4 + r] = gm[r];
    }
    __syncthreads();
#pragma unroll
    for (int r = 0; r < 4; ++r)
        gm[r] = fmaxf(gm[r], redA[cw ^ 1][rw * 16 + lg * 4 + r]);
#pragma unroll
    for (int r = 0; r < 4; ++r) {
        float s = 0.f;
#pragma unroll
        for (int jl = 0; jl < 4; ++jl)
#pragma unroll
            for (int nf = 0; nf < 4; ++nf) {
                float e = __expf(acc[jl][nf][r] - gm[r]);
                acc[jl][nf][r] = e;
                s += e;
            }
#pragma unroll
        for (int o = 1; o < 16; o <<= 1) s += __shfl_xor(s, o, 64);
        gs[r] = s;
    }
    if (lm == 0) {
#pragma unroll
        for (int r = 0; r < 4; ++r) redB[cw][rw * 16 + lg * 4 + r] = gs[r];
    }
    __syncthreads();
#pragma unroll
    for (int r = 0; r < 4; ++r)
        inv[r] = 1.f / (gs[r] + redB[cw ^ 1][rw * 16 + lg * 4 + r]);
#pragma unroll
    for (int jl = 0; jl < 4; ++jl) {
        __syncthreads();
#pragma unroll
        for (int nf = 0; nf < 4; ++nf)
#pragma unroll
            for (int r = 0; r < 4; ++r)
                tl[cw][(rw * 16 + lg * 4 + r) * 72 + nf * 16 + lm] =
                    f2b(acc[jl][nf][r] * inv[r]);
        __syncthreads();
#pragma unroll
        for (int g = tid; g < 512; g += 256) {
            int cwg = g >> 8, rem = g & 255;
            int jtg = cwg * 4 + jl;
            int i_loc = rem >> 3, gj = rem & 7;
            ushort_t tmp[8];
#pragma unroll
            for (int u = 0; u < 8; ++u) tmp[u] = tl[cwg][i_loc * 72 + gj * 8 + u];
            *reinterpret_cast<uint4*>(
                &SHB[((size_t)zc * LL + R0 + i_loc) * LL + jtg * 64 + gj * 8]) =
                *reinterpret_cast<uint4*>(tmp);
        }
#pragma unroll
        for (int g = tid; g < 512; g += 256) {
            int cwg = g >> 8, rem = g & 255;
            int jtg = cwg * 4 + jl;
            int j_loc = rem >> 2, gi = rem & 3;
            ushort_t tmp2[8];
#pragma unroll
            for (int u = 0; u < 8; ++u) tmp2[u] = tl[cwg][(gi * 8 + u) * 72 + j_loc];
            *reinterpret_cast<uint4*>(
                &SHBT[((size_t)zc * LL + jtg * 64 + j_loc) * LL + R0 + gi * 8]) =
                *reinterpret_cast<uint4*>(tmp2);
        }
    }
}

// ---------------- K5: muxed {g12 GEMMs, double-buffered (512 blk)} {corr12 (1024 blk)} ----------------
__global__ __launch_bounds__(256, 4) void k_g12corr(const ushort_t* __restrict__ SHB,
        const ushort_t* __restrict__ SHBT,
        const ushort_t* __restrict__ MPT, const ushort_t* __restrict__ MMT,
        const ushort_t* __restrict__ MP2T, const ushort_t* __restrict__ MM2T,
        const ushort_t* __restrict__ M1Nb, const ushort_t* __restrict__ M2Nb,
        const ushort_t* __restrict__ MPNb, const ushort_t* __restrict__ MMNb,
        const ushort_t* __restrict__ MP2Nb, const ushort_t* __restrict__ MM2Nb,
        const float* __restrict__ dp, float* __restrict__ PG) {
    __shared__ __align__(16) ushort_t sSH[2][4096], sM[2][4096];
    int tid = threadIdx.x;
    int b = blockIdx.x;
    if (b < 512) {
        int it = b & 7, jc = (b >> 3) & 1, zcw = b >> 4;
        int which = zcw >> 4;
        int z = (zcw >> 3) & 1, c = zcw & 7;
        const ushort_t* Amat = which ? SHBT : SHB;
        const ushort_t* TP = which ? MP2T : MPT;
        const ushort_t* TM = which ? MM2T : MMT;
        int w = tid >> 6, lm = tid & 15, lg = (tid & 63) >> 4;
        size_t shbase = ((size_t)(z * HH + c) * LL + it * 64) * LL;
        size_t mbase  = ((size_t)(z * HH + c) * DD) * LL;
        int dgjs = ((it >> 2) == jc) ? (it & 3) : 99;
        int ns = (dgjs < 4) ? 5 : 4;
        auto getsub = [&](int t, const ushort_t*& shp, const ushort_t*& mp,
                          int& j0v, int& passv) {
            int js, pass;
            if (dgjs > 3)            { js = t;        pass = -1; }
            else if (t < dgjs)       { js = t;        pass = -1; }
            else if (t == dgjs)      { js = t;        pass = 0;  }
            else if (t == dgjs + 1)  { js = dgjs;     pass = 1;  }
            else                     { js = t - 1;    pass = -1; }
            int j0 = jc * 256 + js * 64;
            bool useP = (pass == -1)
                        ? (which == 0 ? (j0 < it * 64) : (j0 > it * 64))
                        : (pass == 0);
            shp = Amat + shbase + j0;
            mp  = (useP ? TP : TM) + mbase + j0;
            j0v = j0; passv = pass;
        };
        f32x4 acc[4];
#pragma unroll
        for (int nf = 0; nf < 4; ++nf) acc[nf] = {0.f,0.f,0.f,0.f};
        {
            const ushort_t *shp, *mp; int j0v, pv;
            getsub(0, shp, mp, j0v, pv);
            stage64a(sSH[0], shp, LL, tid);
            stage64a(sM[0], mp, LL, tid);
        }
        for (int t = 0; t < ns; ++t) {
            __syncthreads();
            if (t + 1 < ns) {
                const ushort_t *shp, *mp; int j0v, pv;
                getsub(t + 1, shp, mp, j0v, pv);
                stage64a(sSH[(t + 1) & 1], shp, LL, tid);
                stage64a(sM[(t + 1) & 1], mp, LL, tid);
            }
            const ushort_t *shp_, *mp_; int j0v, pv;
            getsub(t, shp_, mp_, j0v, pv);
            const ushort_t* sshx = sSH[t & 1];
            const ushort_t* smx = sM[t & 1];
#pragma unroll
            for (int ks = 0; ks < 2; ++ks) {
                int kc = ks * 32 + lg * 8;
                int jb = j0v + kc;
                bf16x8 af = frag(sshx, w * 16 + lm, kc);
                if (pv >= 0) {
                    int i = it * 64 + w * 16 + lm;
                    int cnt = (which == 0) ? iclamp(i - jb, 0, 8) : iclamp(i + 1 - jb, 0, 8);
                    af = maskfrag(af, cnt, (pv == 0) == (which == 0));
                }
#pragma unroll
                for (int nf = 0; nf < 4; ++nf)
                    acc[nf] = MFMA(af, frag(smx, nf * 16 + lm, kc), acc[nf]);
            }
        }
        int slot = which * 16 + c * 2 + jc;
#pragma unroll
        for (int nf = 0; nf < 4; ++nf)
#pragma unroll
            for (int r = 0; r < 4; ++r) {
                int i = it * 64 + w * 16 + lg * 4 + r;
                int a = nf * 16 + lm;
                PG[((size_t)(slot * BB + z) * LL + i) * DD + a] = acc[nf][r];
            }
    } else {
        int bid = b - 512;
        int which = bid >> 9; bid &= 511;
        int w = bid * 4 + (tid >> 6);
        int lane = tid & 63;
        int ch = w & 1, i = (w >> 1) & 511, z = w >> 10;
        const ushort_t* Mx = which ? M2Nb : M1Nb;
        const ushort_t* MPb = which ? MP2Nb : MPNb;
        const ushort_t* MMb = which ? MM2Nb : MMNb;
        float acc = 0.f;
        for (int cc = 0; cc < 4; ++cc) {
            int c = ch * 4 + cc;
#pragma unroll
            for (int d = -3; d <= 3; ++d) {
                int j = which ? i + d : i - d;
                if (j < 0 || j >= LL) continue;
                float qh = which ? b2f(SHB[(((size_t)z * HH + c) * LL + j) * LL + i])
                                 : b2f(SHB[(((size_t)z * HH + c) * LL + i) * LL + j]);
                int idx = d < 0 ? d + 9 : d;
                float e = 0.f;
                if (idx != 0) {
#pragma unroll
                    for (int k = 0; k < 4; ++k)
                        e += dp[(idx - 1) * 4 + k] *
                             b2f(Mx[((((size_t)z * KK + k) * HH + c) * LL + j) * DD + lane]);
                }
                const ushort_t* mb = (d > 0) ? MPb : MMb;
                float mn = b2f(mb[(((size_t)z * HH + c) * LL + j) * DD + lane]);
                acc += qh * (e - mn);
            }
        }
        int slot = 32 + which * 2 + ch;
        PG[(((size_t)slot * BB + z) * LL + i) * DD + lane] = acc;
    }
}

// ---------------- K6a: mid-iteration update: q = x + msgs -> softmax -> Qz/QzB + next QG ----------------
__global__ __launch_bounds__(256) void k_update_sm(const float* __restrict__ x,
                         const float* __restrict__ PG, const float* __restrict__ QG,
                         const float* __restrict__ gp, const int* __restrict__ mask,
                         float* __restrict__ Qz, ushort_t* __restrict__ QzB,
                         float* __restrict__ QGn) {
    __shared__ __align__(16) float gpS[64][68];
    int tid = threadIdx.x;
#pragma unroll
    for (int idx = tid; idx < 4096; idx += 256) gpS[idx >> 6][idx & 63] = gp[idx];
    __syncthreads();
    int row = blockIdx.x * 4 + (tid >> 6);
    int a = tid & 63;
    float acc = x[row * DD + a];
    float qgv = QG[row * GG + a];
#pragma unroll 8
    for (int g = 0; g < 64; ++g) acc += __shfl(qgv, g, 64) * gpS[g][a];
#pragma unroll 6
    for (int s = 0; s < NSLOT; ++s) acc += PG[((size_t)s * BB * LL + row) * DD + a];
    float m = acc;
#pragma unroll
    for (int o = 32; o > 0; o >>= 1) m = fmaxf(m, __shfl_xor(m, o, 64));
    float e = __expf(acc - m);
    float s2 = e;
#pragma unroll
    for (int o = 32; o > 0; o >>= 1) s2 += __shfl_xor(s2, o, 64);
    float r = e / s2;
    Qz[row * DD + a] = r;
    QzB[row * DD + a] = f2b(r);
    // next-iteration qg from in-register row
    float sg = 0.f;
#pragma unroll 8
    for (int g = 0; g < 64; ++g) sg += __shfl(r, g, 64) * gpS[a][g];
    if (mask[row] == 0) sg = NEGV;
    float mg = sg;
#pragma unroll
    for (int o = 32; o > 0; o >>= 1) mg = fmaxf(mg, __shfl_xor(mg, o, 64));
    float eg = __expf(sg - mg);
    float sumg = eg;
#pragma unroll
    for (int o = 32; o > 0; o >>= 1) sumg += __shfl_xor(sumg, o, 64);
    QGn[row * GG + a] = eg / sumg;
}

// ---------------- K6b: final update: out = x + msgs ----------------
__global__ __launch_bounds__(256) void k_update_fin(const float* __restrict__ x,
                         const float* __restrict__ PG, const float* __restrict__ QG,
                         const float* __restrict__ gp, float* __restrict__ outq) {
    __shared__ __align__(16) float gpS[64][68];
    int tid = threadIdx.x;
#pragma unroll
    for (int idx = tid; idx < 4096; idx += 256) gpS[idx >> 6][idx & 63] = gp[idx];
    __syncthreads();
    int row = blockIdx.x * 4 + (tid >> 6);
    int a = tid & 63;
    float acc = x[row * DD + a];
    float qgv = QG[row * GG + a];
#pragma unroll 8
    for (int g = 0; g < 64; ++g) acc += __shfl(qgv, g, 64) * gpS[g][a];
#pragma unroll 6
    for (int s = 0; s < NSLOT; ++s) acc += PG[((size_t)s * BB * LL + row) * DD + a];
    outq[row * DD + a] = acc;
}

extern "C" void kernel_launch(void* const* d_in, const int* in_sizes, int n_in,
                              void* d_out, int out_size, void* d_ws, size_t ws_size,
                              hipStream_t stream) {
    const float* x    = (const float*)d_in[0];
    const int*   mask = (const int*)d_in[1];
    const float* dp   = (const float*)d_in[2];
    const float* T    = (const float*)d_in[3];
    const float* gp   = (const float*)d_in[4];
    float* out = (float*)d_out;

    float* p = (float*)d_ws;
    float* Qz = p;                        p += 65536;
    ushort_t* QzB = (ushort_t*)p;         p += 32768;
    ushort_t* TB1 = (ushort_t*)p;         p += 65536;
    ushort_t* TB2 = (ushort_t*)p;         p += 65536;
    ushort_t* M1Nb = (ushort_t*)p;        p += 1048576;
    ushort_t* M2Nb = (ushort_t*)p;        p += 1048576;
    ushort_t* MPNb  = (ushort_t*)p;       p += 262144;
    ushort_t* MMNb  = (ushort_t*)p;       p += 262144;
    ushort_t* MP2Nb = (ushort_t*)p;       p += 262144;
    ushort_t* MM2Nb = (ushort_t*)p;       p += 262144;
    ushort_t* MPT   = (ushort_t*)p;       p += 262144;
    ushort_t* MMT   = (ushort_t*)p;       p += 262144;
    ushort_t* MP2T  = (ushort_t*)p;       p += 262144;
    ushort_t* MM2T  = (ushort_t*)p;       p += 262144;
    float* BAND = p;                      p += 65536;
    ushort_t* SHB  = (ushort_t*)p;        p += 2097152;
    ushort_t* SHBT = (ushort_t*)p;        p += 2097152;
    float* QG   = p;                      p += 65536;
    float* QG1  = p;                      p += 65536;
    float* PG   = p;                      p += (size_t)NSLOT * 65536;

    hipLaunchKernelGGL(k_prep, dim3(288), dim3(256), 0, stream, T, x, gp, mask,
                       Qz, QzB, TB1, TB2, QG);

    for (int iter = 0; iter < 2; ++iter) {
        float* qgCur = (iter == 0) ? QG : QG1;
        hipLaunchKernelGGL(k_Mcoll, dim3(8, 16), dim3(256), 0, stream, QzB, TB1, TB2, dp, Qz,
                           M1Nb, M2Nb, MPNb, MMNb, MP2Nb, MM2Nb, MPT, MMT, MP2T, MM2T, BAND);
        hipLaunchKernelGGL(k_shsm32, dim3(16, 16), dim3(256), 0, stream, QzB, MPNb, MMNb, BAND, mask,
                           SHB, SHBT);
        hipLaunchKernelGGL(k_g12corr, dim3(1536), dim3(256), 0, stream, SHB, SHBT,
                           MPT, MMT, MP2T, MM2T, M1Nb, M2Nb,
                           MPNb, MMNb, MP2Nb, MM2Nb, dp, PG);
        if (iter == 0)
            hipLaunchKernelGGL(k_update_sm, dim3(256), dim3(256), 0, stream, x, PG, qgCur, gp, mask,
                               Qz, QzB, QG1);
        else
            hipLaunchKernelGGL(k_update_fin, dim3(256), dim3(256), 0, stream, x, PG, qgCur, gp, out);
    }
}